// Round 10
// baseline (97.748 us; speedup 1.0000x reference)
//
#include <hip/hip_runtime.h>
#include <math.h>

#define EPS 1e-6f

typedef float f32x4 __attribute__((ext_vector_type(4)));

// Input: feat_map [T=32][D=256][H=56][W=56] fp32. float4 view: per-t 200704; slice 784.
// 25088 = 32*784 = 98 blocks * 256 threads.
//
// loc_reduce: 3136 blocks x 256 threads (8 blocks/CU resident = 32 waves/CU, max TLP).
//   b -> (t = b/98, sub = b%98). Thread owns float4 index g = sub*256+tid in t's
//   region; reads j = g + 25088*i, i=0..7 (stride ≡ 0 mod 784 -> fixed pos/h/v,
//   register accumulation; 2 loads paired per unroll step for ILP). Per t, the 98
//   blocks sweep one contiguous 392 KB window in lockstep -> 32 contiguous sliding
//   fronts chip-wide. Epilogue: LDS histogram (224 floats) -> disjoint ws partial.
//
// ws partials: [b][arr(0:s1h,1:s2h,2:s1w,3:s2w)][56]  (3136*224 floats = 2.81 MB)
// out: [0]=tot, then log10(ga1)[32*56], ga2, ga3, ga4.

__global__ __launch_bounds__(256) void loc_reduce(const float* __restrict__ f,
                                                  float* __restrict__ ws) {
    const int b   = blockIdx.x;          // 0..3135
    const int t   = b / 98;
    const int sub = b % 98;
    const int tid = threadIdx.x;
    const int g   = sub * 256 + tid;     // 0..25087 within t
    const int pos = g % 784;             // fixed
    const int h   = pos / 14;
    const int v   = pos % 14;

    const f32x4* p = reinterpret_cast<const f32x4*>(f) + (size_t)t * 200704 + g;

    float s10 = 0.f, s11 = 0.f, s12 = 0.f, s13 = 0.f;
    float s20 = 0.f, s21 = 0.f, s22 = 0.f, s23 = 0.f;

    #pragma unroll
    for (int i = 0; i < 4; ++i) {
        f32x4 x = p[(size_t)(2 * i) * 25088];
        f32x4 y = p[(size_t)(2 * i + 1) * 25088];
        s10 += x.x; s11 += x.y; s12 += x.z; s13 += x.w;
        s20 += x.x * x.x; s21 += x.y * x.y; s22 += x.z * x.z; s23 += x.w * x.w;
        s10 += y.x; s11 += y.y; s12 += y.z; s13 += y.w;
        s20 += y.x * y.x; s21 += y.y * y.y; s22 += y.z * y.z; s23 += y.w * y.w;
    }

    __shared__ float ls[224];
    if (tid < 224) ls[tid] = 0.f;
    __syncthreads();

    atomicAdd(&ls[h],      s10 + s11 + s12 + s13);
    atomicAdd(&ls[56 + h], s20 + s21 + s22 + s23);
    atomicAdd(&ls[112 + 4 * v + 0], s10);
    atomicAdd(&ls[112 + 4 * v + 1], s11);
    atomicAdd(&ls[112 + 4 * v + 2], s12);
    atomicAdd(&ls[112 + 4 * v + 3], s13);
    atomicAdd(&ls[168 + 4 * v + 0], s20);
    atomicAdd(&ls[168 + 4 * v + 1], s21);
    atomicAdd(&ls[168 + 4 * v + 2], s22);
    atomicAdd(&ls[168 + 4 * v + 3], s23);
    __syncthreads();

    if (tid < 224) ws[(size_t)b * 224 + tid] = ls[tid];
}

__global__ __launch_bounds__(1024) void loc_finalize(const float* __restrict__ ws,
                                                     float* __restrict__ out) {
    __shared__ float sums[7168];  // [t][arr][56]
    const int tid = threadIdx.x;

    // Phase 1: fold the 98 sub-block partials per t (7 outputs/thread).
    #pragma unroll
    for (int k = 0; k < 7; ++k) {
        const int o  = tid + 1024 * k;   // o = t*224 + k2
        const int t  = o / 224;
        const int k2 = o % 224;
        float a = 0.f;
        for (int sub = 0; sub < 98; ++sub)
            a += ws[(size_t)(t * 98 + sub) * 224 + k2];
        sums[o] = a;
    }
    __syncthreads();

    // Phase 2: 64 threads = (t 0..31) x (H-axis / W-axis); serial 56-elem scans.
    if (tid < 64) {
        const int t    = tid & 31;
        const bool isW = tid >= 32;

        const float* s1 = &sums[t * 224 + (isW ? 112 : 0)];
        const float* s2 = &sums[t * 224 + (isW ? 168 : 56)];
        float* osuf = out + 1 + (isW ? 3584 : 0)    + t * 56;  // ga1 / ga3
        float* opre = out + 1 + (isW ? 5376 : 1792) + t * 56;  // ga2 / ga4

        const float n_per = 14336.f;  // D*W == D*H
        float part = 0.f;

        float a1 = 0.f, a2 = 0.f;
        for (int i = 55; i >= 0; --i) {            // suffix
            a1 += s1[i]; a2 += s2[i];
            const float n  = n_per * (float)(56 - i);
            const float ga = sqrtf(a2 + 2.0f * EPS * a1 + (EPS * EPS) * n);
            osuf[i] = log10f(ga);
            part += ga + EPS;
        }
        a1 = 0.f; a2 = 0.f;
        for (int i = 0; i < 56; ++i) {             // prefix
            a1 += s1[i]; a2 += s2[i];
            const float n  = n_per * (float)(i + 1);
            const float ga = sqrtf(a2 + 2.0f * EPS * a1 + (EPS * EPS) * n);
            opre[i] = log10f(ga);
            part += ga + EPS;
        }

        #pragma unroll
        for (int off = 32; off; off >>= 1) part += __shfl_down(part, off);
        if (tid == 0) out[0] = part * (1.0f / 128.0f);  // /T /4
    }
}

extern "C" void kernel_launch(void* const* d_in, const int* in_sizes, int n_in,
                              void* d_out, int out_size, void* d_ws, size_t ws_size,
                              hipStream_t stream) {
    const float* f = (const float*)d_in[0];
    float* out = (float*)d_out;
    float* ws  = (float*)d_ws;

    loc_reduce<<<dim3(3136), dim3(256), 0, stream>>>(f, ws);
    loc_finalize<<<dim3(1), dim3(1024), 0, stream>>>(ws, out);
}